// Round 1
// baseline (304.170 us; speedup 1.0000x reference)
//
#include <hip/hip_runtime.h>
#include <hip/hip_bf16.h>

#define B_ 2
#define T_ 2048
#define C_ 1024
#define NH_ 16
#define NKV_ 4
#define HD_ 64
#define NQKV_ 1536           // (NH + 2*NKV) * HD
#define M_ 4096              // B_ * T_

typedef __attribute__((ext_vector_type(8))) __bf16 bf16x8;
typedef __attribute__((ext_vector_type(4))) __bf16 bf16x4;
typedef __attribute__((ext_vector_type(4))) float f32x4;
typedef __attribute__((ext_vector_type(4))) unsigned int u32x4;

// ---------------- cast x (fp32 -> bf16), 4 elems/thread ----------------
__global__ __launch_bounds__(256) void cast_x_kernel(const float* __restrict__ in,
                                                     __bf16* __restrict__ out) {
  const int i = blockIdx.x * 256 + threadIdx.x;
  const float4 v = ((const float4*)in)[i];
  bf16x4 o;
  o.x = (__bf16)v.x; o.y = (__bf16)v.y; o.z = (__bf16)v.z; o.w = (__bf16)v.w;
  ((bf16x4*)out)[i] = o;
}

// ---------- transpose + cast: in [K][N] fp32 -> out [N][K] bf16 ----------
__global__ __launch_bounds__(256) void transpose_cast_kernel(const float* __restrict__ in,
                                                             __bf16* __restrict__ out,
                                                             int K, int N) {
  __shared__ __bf16 tile[64][72];  // [n_local][k_local], padded
  const int n0 = blockIdx.x * 64, k0 = blockIdx.y * 64;
  const int tid = threadIdx.x;
  const int tr = tid >> 4, tc4 = (tid & 15) << 2;
  #pragma unroll
  for (int p = 0; p < 4; ++p) {
    const int k = k0 + p * 16 + tr;
    const float4 v = *(const float4*)&in[(size_t)k * N + n0 + tc4];
    tile[tc4 + 0][p * 16 + tr] = (__bf16)v.x;
    tile[tc4 + 1][p * 16 + tr] = (__bf16)v.y;
    tile[tc4 + 2][p * 16 + tr] = (__bf16)v.z;
    tile[tc4 + 3][p * 16 + tr] = (__bf16)v.w;
  }
  __syncthreads();
  #pragma unroll
  for (int p = 0; p < 4; ++p) {
    const int n = n0 + p * 16 + tr;
    bf16x4 o;
    o.x = tile[p * 16 + tr][tc4 + 0];
    o.y = tile[p * 16 + tr][tc4 + 1];
    o.z = tile[p * 16 + tr][tc4 + 2];
    o.w = tile[p * 16 + tr][tc4 + 3];
    *(bf16x4*)&out[(size_t)n * K + k0 + tc4] = o;
  }
}

// ---------------- RoPE cos/sin tables [T][32] fp32 ----------------
__global__ __launch_bounds__(256) void rope_table_kernel(float* __restrict__ cosT,
                                                         float* __restrict__ sinT) {
  const int idx = blockIdx.x * 256 + threadIdx.x;  // T*32 total
  const int t = idx >> 5, i = idx & 31;
  const float inv = powf(10000.0f, -(float)i * (1.0f / 32.0f));
  const float ang = (float)t * inv;
  cosT[idx] = cosf(ang);
  sinT[idx] = sinf(ang);
}

// ------- bf16 TN GEMM: A[M][K] * Bt[N][K]^T -> C[M][N] fp32 -------
// 128x128 tile, BK=64, 4 waves (2x2), reg-staged LDS with XOR swizzle.
__global__ __launch_bounds__(256) void gemm_tn_kernel(const __bf16* __restrict__ A,
                                                      const __bf16* __restrict__ Bt,
                                                      float* __restrict__ C, int N, int K) {
  __shared__ __align__(16) __bf16 lA[128 * 64];
  __shared__ __align__(16) __bf16 lB[128 * 64];
  const int tid = threadIdx.x;
  const int lane = tid & 63;
  const int wave = tid >> 6;
  const int wr = wave >> 1, wc = wave & 1;
  const int m0 = blockIdx.y * 128, n0 = blockIdx.x * 128;
  const int srow = tid >> 3, kc = tid & 7;  // staging: 8 threads/row, 16B chunks
  const int r16 = lane & 15, g = lane >> 4;
  f32x4 acc[4][4] = {};
  for (int k0 = 0; k0 < K; k0 += 64) {
    u32x4 ra[4], rb[4];
    #pragma unroll
    for (int p = 0; p < 4; ++p) {
      const int row = p * 32 + srow;
      ra[p] = *(const u32x4*)&A[(size_t)(m0 + row) * K + k0 + kc * 8];
      rb[p] = *(const u32x4*)&Bt[(size_t)(n0 + row) * K + k0 + kc * 8];
    }
    __syncthreads();  // prior iter's ds_reads done before overwrite
    #pragma unroll
    for (int p = 0; p < 4; ++p) {
      const int row = p * 32 + srow;
      const int sw = kc ^ (row & 7);  // bank-conflict swizzle (G4)
      *(u32x4*)&lA[row * 64 + sw * 8] = ra[p];
      *(u32x4*)&lB[row * 64 + sw * 8] = rb[p];
    }
    __syncthreads();
    #pragma unroll
    for (int ks = 0; ks < 64; ks += 32) {
      bf16x8 af[4], bfr[4];
      const int kch = (ks >> 3) + g;
      #pragma unroll
      for (int mi = 0; mi < 4; ++mi) {
        const int row = wr * 64 + mi * 16 + r16;
        af[mi] = *(const bf16x8*)&lA[row * 64 + (kch ^ (row & 7)) * 8];
      }
      #pragma unroll
      for (int ni = 0; ni < 4; ++ni) {
        const int row = wc * 64 + ni * 16 + r16;
        bfr[ni] = *(const bf16x8*)&lB[row * 64 + (kch ^ (row & 7)) * 8];
      }
      #pragma unroll
      for (int mi = 0; mi < 4; ++mi)
        #pragma unroll
        for (int ni = 0; ni < 4; ++ni)
          acc[mi][ni] = __builtin_amdgcn_mfma_f32_16x16x32_bf16(af[mi], bfr[ni], acc[mi][ni], 0, 0, 0);
    }
  }
  // epilogue: D layout col=lane&15, row=(lane>>4)*4+j
  #pragma unroll
  for (int mi = 0; mi < 4; ++mi) {
    const int r0 = m0 + wr * 64 + mi * 16 + g * 4;
    #pragma unroll
    for (int ni = 0; ni < 4; ++ni) {
      const int c = n0 + wc * 64 + ni * 16 + r16;
      #pragma unroll
      for (int j = 0; j < 4; ++j)
        C[(size_t)(r0 + j) * N + c] = acc[mi][ni][j];
    }
  }
}

// ---- RoPE on q,k (from fp32 qkv) -> Q[b][h][t][d], K[b][kvh][t][d] bf16 ----
__global__ __launch_bounds__(256) void rope_qk_kernel(const float* __restrict__ qkv,
                                                      const float* __restrict__ cosT,
                                                      const float* __restrict__ sinT,
                                                      __bf16* __restrict__ Q,
                                                      __bf16* __restrict__ Kb) {
  const int idx = blockIdx.x * 256 + threadIdx.x;  // M_*(NH+NKV)*32 total
  const int i = idx & 31;
  const int rest = idx >> 5;
  const int head = rest % (NH_ + NKV_);
  const int row = rest / (NH_ + NKV_);
  const int b = row >> 11, t = row & 2047;
  const float c = cosT[t * 32 + i], s = sinT[t * 32 + i];
  if (head < NH_) {
    const float* p = &qkv[(size_t)row * NQKV_ + head * HD_ + 2 * i];
    const float o1 = p[0] * c - p[1] * s;
    const float o2 = p[0] * s + p[1] * c;
    __bf16* q = &Q[(((size_t)b * NH_ + head) * T_ + t) * HD_ + 2 * i];
    q[0] = (__bf16)o1; q[1] = (__bf16)o2;
  } else {
    const int kh = head - NH_;
    const float* p = &qkv[(size_t)row * NQKV_ + NH_ * HD_ + kh * HD_ + 2 * i];
    const float o1 = p[0] * c - p[1] * s;
    const float o2 = p[0] * s + p[1] * c;
    __bf16* k = &Kb[(((size_t)b * NKV_ + kh) * T_ + t) * HD_ + 2 * i];
    k[0] = (__bf16)o1; k[1] = (__bf16)o2;
  }
}

// ---- V transpose: qkv v-part -> Vt[b][kvh][d][t] bf16 (LDS tiled) ----
__global__ __launch_bounds__(256) void v_transpose_kernel(const float* __restrict__ qkv,
                                                          __bf16* __restrict__ Vt) {
  __shared__ __bf16 tile[64][72];  // [d][t_local], padded
  const int blk = blockIdx.x;      // B*NKV*(T/64)
  const int t0 = (blk & 31) * 64;
  const int kvh = (blk >> 5) & 3;
  const int b = blk >> 7;
  const int tid = threadIdx.x;
  const int tr = tid >> 4, c4 = (tid & 15) << 2;
  #pragma unroll
  for (int p = 0; p < 4; ++p) {
    const int t = t0 + p * 16 + tr;
    const float4 v = *(const float4*)&qkv[(size_t)(b * T_ + t) * NQKV_ + (NH_ + NKV_) * HD_ + kvh * HD_ + c4];
    tile[c4 + 0][p * 16 + tr] = (__bf16)v.x;
    tile[c4 + 1][p * 16 + tr] = (__bf16)v.y;
    tile[c4 + 2][p * 16 + tr] = (__bf16)v.z;
    tile[c4 + 3][p * 16 + tr] = (__bf16)v.w;
  }
  __syncthreads();
  #pragma unroll
  for (int p = 0; p < 4; ++p) {
    const int d = p * 16 + tr;
    bf16x4 o;
    o.x = tile[d][c4 + 0]; o.y = tile[d][c4 + 1];
    o.z = tile[d][c4 + 2]; o.w = tile[d][c4 + 3];
    *(bf16x4*)&Vt[(((size_t)b * NKV_ + kvh) * HD_ + d) * T_ + t0 + c4] = o;
  }
}

// ---- flash attention: 1 wave per (b,h,16 q-rows), KVBLK=32, online softmax ----
__global__ __launch_bounds__(64) void attn_kernel(const __bf16* __restrict__ Q,
                                                  const __bf16* __restrict__ Kb,
                                                  const __bf16* __restrict__ Vt,
                                                  __bf16* __restrict__ Y) {
  __shared__ __align__(16) __bf16 pS[16 * 32];
  const int lane = threadIdx.x;
  const int r16 = lane & 15, g = lane >> 4;
  const int q0 = blockIdx.x * 16;
  const int bh = blockIdx.y;
  const int b = bh >> 4, h = bh & 15;
  const int kvh = h >> 2;  // GQA: rep = 4
  const __bf16* Qp = Q + ((size_t)b * NH_ + h) * T_ * HD_;
  const __bf16* Kp = Kb + ((size_t)b * NKV_ + kvh) * T_ * HD_;
  const __bf16* Vp = Vt + ((size_t)b * NKV_ + kvh) * HD_ * T_;

  // Q fragments (A-layout: row=lane&15, k=(lane>>4)*8+j), pre-scaled by 1/8 (exact)
  bf16x8 qf[2];
  {
    const bf16x8 t0 = *(const bf16x8*)&Qp[(size_t)(q0 + r16) * HD_ + g * 8];
    const bf16x8 t1 = *(const bf16x8*)&Qp[(size_t)(q0 + r16) * HD_ + 32 + g * 8];
    #pragma unroll
    for (int j = 0; j < 8; ++j) {
      qf[0][j] = (__bf16)((float)t0[j] * 0.125f);
      qf[1][j] = (__bf16)((float)t1[j] * 0.125f);
    }
  }
  f32x4 o[4] = {};
  float m[4], l[4];
  #pragma unroll
  for (int j = 0; j < 4; ++j) { m[j] = -__builtin_inff(); l[j] = 0.0f; }

  const int ntiles = (q0 + 47) >> 5;
  for (int tile = 0; tile < ntiles; ++tile) {
    const int kv0 = tile << 5;
    f32x4 s[2] = {};
    #pragma unroll
    for (int half = 0; half < 2; ++half) {
      const __bf16* kbase = &Kp[(size_t)(kv0 + half * 16 + r16) * HD_ + g * 8];
      const bf16x8 k0 = *(const bf16x8*)kbase;
      const bf16x8 k1 = *(const bf16x8*)(kbase + 32);
      s[half] = __builtin_amdgcn_mfma_f32_16x16x32_bf16(qf[0], k0, s[half], 0, 0, 0);
      s[half] = __builtin_amdgcn_mfma_f32_16x16x32_bf16(qf[1], k1, s[half], 0, 0, 0);
    }
    if (kv0 + 31 > q0) {  // causal mask (diagonal tiles only)
      #pragma unroll
      for (int j = 0; j < 4; ++j) {
        const int qr = q0 + g * 4 + j;
        if (kv0 + r16 > qr)      s[0][j] = -__builtin_inff();
        if (kv0 + 16 + r16 > qr) s[1][j] = -__builtin_inff();
      }
    }
    // online softmax, rows owned per-(g,j), reduce across 16 lanes
    #pragma unroll
    for (int j = 0; j < 4; ++j) {
      float pm = fmaxf(s[0][j], s[1][j]);
      #pragma unroll
      for (int off = 8; off; off >>= 1) pm = fmaxf(pm, __shfl_xor(pm, off, 16));
      const float nm = fmaxf(m[j], pm);
      const float p0 = __expf(s[0][j] - nm);
      const float p1 = __expf(s[1][j] - nm);
      const float sc = __expf(m[j] - nm);
      m[j] = nm;
      float rs = p0 + p1;
      #pragma unroll
      for (int off = 8; off; off >>= 1) rs += __shfl_xor(rs, off, 16);
      l[j] = l[j] * sc + rs;
      #pragma unroll
      for (int nf = 0; nf < 4; ++nf) o[nf][j] *= sc;
      const int r = g * 4 + j;
      pS[r * 32 + r16] = (__bf16)p0;
      pS[r * 32 + 16 + r16] = (__bf16)p1;
    }
    __syncthreads();  // single wave: orders ds_write -> ds_read
    const bf16x8 pf = *(const bf16x8*)&pS[r16 * 32 + g * 8];
    #pragma unroll
    for (int nf = 0; nf < 4; ++nf) {
      const bf16x8 vf = *(const bf16x8*)&Vp[(size_t)(nf * 16 + r16) * T_ + kv0 + g * 8];
      o[nf] = __builtin_amdgcn_mfma_f32_16x16x32_bf16(pf, vf, o[nf], 0, 0, 0);
    }
    __syncthreads();  // WAR on pS before next tile
  }
  // epilogue -> Y[b][t][h][d] bf16 (row-major [M][C] for GEMM2)
  #pragma unroll
  for (int j = 0; j < 4; ++j) {
    const float inv = 1.0f / l[j];
    const int t = q0 + g * 4 + j;
    #pragma unroll
    for (int nf = 0; nf < 4; ++nf) {
      const int d = nf * 16 + r16;
      Y[(((size_t)b * T_ + t) * NH_ + h) * HD_ + d] = (__bf16)(o[nf][j] * inv);
    }
  }
}

extern "C" void kernel_launch(void* const* d_in, const int* in_sizes, int n_in,
                              void* d_out, int out_size, void* d_ws, size_t ws_size,
                              hipStream_t stream) {
  const float* x = (const float*)d_in[0];
  const float* Wqkv = (const float*)d_in[1];
  const float* Wproj = (const float*)d_in[2];
  float* out = (float*)d_out;

  char* ws = (char*)d_ws;
  size_t off = 0;
  auto alloc = [&](size_t bytes) {
    char* p = ws + off;
    off += (bytes + 255) & ~(size_t)255;
    return p;
  };
  __bf16* xb     = (__bf16*)alloc((size_t)M_ * C_ * 2);          // 8 MB
  __bf16* wqkvT  = (__bf16*)alloc((size_t)NQKV_ * C_ * 2);       // 3 MB
  __bf16* wprojT = (__bf16*)alloc((size_t)C_ * C_ * 2);          // 2 MB
  float*  cosT   = (float*)alloc((size_t)T_ * 32 * 4);
  float*  sinT   = (float*)alloc((size_t)T_ * 32 * 4);
  float*  qkv    = (float*)alloc((size_t)M_ * NQKV_ * 4);        // 25 MB
  __bf16* Qb     = (__bf16*)alloc((size_t)B_ * NH_ * T_ * HD_ * 2);
  __bf16* Kb     = (__bf16*)alloc((size_t)B_ * NKV_ * T_ * HD_ * 2);
  __bf16* Vt     = (__bf16*)alloc((size_t)B_ * NKV_ * T_ * HD_ * 2);
  __bf16* Yb     = (__bf16*)alloc((size_t)M_ * C_ * 2);          // 8 MB

  hipLaunchKernelGGL(cast_x_kernel, dim3(M_ * C_ / 4 / 256), dim3(256), 0, stream, x, xb);
  hipLaunchKernelGGL(transpose_cast_kernel, dim3(NQKV_ / 64, C_ / 64), dim3(256), 0, stream,
                     Wqkv, wqkvT, C_, NQKV_);
  hipLaunchKernelGGL(transpose_cast_kernel, dim3(C_ / 64, C_ / 64), dim3(256), 0, stream,
                     Wproj, wprojT, C_, C_);
  hipLaunchKernelGGL(rope_table_kernel, dim3(T_ * 32 / 256), dim3(256), 0, stream, cosT, sinT);
  hipLaunchKernelGGL(gemm_tn_kernel, dim3(NQKV_ / 128, M_ / 128), dim3(256), 0, stream,
                     xb, wqkvT, qkv, NQKV_, C_);
  hipLaunchKernelGGL(rope_qk_kernel, dim3(M_ * (NH_ + NKV_) * 32 / 256), dim3(256), 0, stream,
                     qkv, cosT, sinT, Qb, Kb);
  hipLaunchKernelGGL(v_transpose_kernel, dim3(B_ * NKV_ * (T_ / 64)), dim3(256), 0, stream,
                     qkv, Vt);
  hipLaunchKernelGGL(attn_kernel, dim3(T_ / 16, B_ * NH_), dim3(64), 0, stream, Qb, Kb, Vt, Yb);
  hipLaunchKernelGGL(gemm_tn_kernel, dim3(C_ / 128, M_ / 128), dim3(256), 0, stream,
                     Yb, wprojT, out, C_, C_);
}

// Round 2
// 188.946 us; speedup vs baseline: 1.6098x; 1.6098x over previous
//
#include <hip/hip_runtime.h>
#include <hip/hip_bf16.h>

#define B_ 2
#define T_ 2048
#define C_ 1024
#define NH_ 16
#define NKV_ 4
#define HD_ 64
#define NQKV_ 1536           // (NH + 2*NKV) * HD
#define M_ 4096              // B_ * T_

typedef __attribute__((ext_vector_type(8))) __bf16 bf16x8;
typedef __attribute__((ext_vector_type(4))) __bf16 bf16x4;
typedef __attribute__((ext_vector_type(4))) float f32x4;
typedef __attribute__((ext_vector_type(4))) unsigned int u32x4;

// ---------------- cast x (fp32 -> bf16), 4 elems/thread ----------------
__global__ __launch_bounds__(256) void cast_x_kernel(const float* __restrict__ in,
                                                     __bf16* __restrict__ out) {
  const int i = blockIdx.x * 256 + threadIdx.x;
  const float4 v = ((const float4*)in)[i];
  bf16x4 o;
  o.x = (__bf16)v.x; o.y = (__bf16)v.y; o.z = (__bf16)v.z; o.w = (__bf16)v.w;
  ((bf16x4*)out)[i] = o;
}

// ---------- transpose + cast: in [K][N] fp32 -> out [N][K] bf16 ----------
__global__ __launch_bounds__(256) void transpose_cast_kernel(const float* __restrict__ in,
                                                             __bf16* __restrict__ out,
                                                             int K, int N) {
  __shared__ __bf16 tile[64][72];  // [n_local][k_local], padded
  const int n0 = blockIdx.x * 64, k0 = blockIdx.y * 64;
  const int tid = threadIdx.x;
  const int tr = tid >> 4, tc4 = (tid & 15) << 2;
  #pragma unroll
  for (int p = 0; p < 4; ++p) {
    const int k = k0 + p * 16 + tr;
    const float4 v = *(const float4*)&in[(size_t)k * N + n0 + tc4];
    tile[tc4 + 0][p * 16 + tr] = (__bf16)v.x;
    tile[tc4 + 1][p * 16 + tr] = (__bf16)v.y;
    tile[tc4 + 2][p * 16 + tr] = (__bf16)v.z;
    tile[tc4 + 3][p * 16 + tr] = (__bf16)v.w;
  }
  __syncthreads();
  #pragma unroll
  for (int p = 0; p < 4; ++p) {
    const int n = n0 + p * 16 + tr;
    bf16x4 o;
    o.x = tile[p * 16 + tr][tc4 + 0];
    o.y = tile[p * 16 + tr][tc4 + 1];
    o.z = tile[p * 16 + tr][tc4 + 2];
    o.w = tile[p * 16 + tr][tc4 + 3];
    *(bf16x4*)&out[(size_t)n * K + k0 + tc4] = o;
  }
}

// ---------------- RoPE cos/sin tables [T][32] fp32 ----------------
__global__ __launch_bounds__(256) void rope_table_kernel(float* __restrict__ cosT,
                                                         float* __restrict__ sinT) {
  const int idx = blockIdx.x * 256 + threadIdx.x;  // T*32 total
  const int t = idx >> 5, i = idx & 31;
  const float inv = powf(10000.0f, -(float)i * (1.0f / 32.0f));
  const float ang = (float)t * inv;
  cosT[idx] = cosf(ang);
  sinT[idx] = sinf(ang);
}

// ------- bf16 TN GEMM: A[M][K] * Bt[N][K]^T -> C[M][N] fp32 -------
// 128x128 tile, BK=64, 4 waves (2x2), reg-staged LDS with XOR swizzle.
__global__ __launch_bounds__(256) void gemm_tn_kernel(const __bf16* __restrict__ A,
                                                      const __bf16* __restrict__ Bt,
                                                      float* __restrict__ C, int N, int K) {
  __shared__ __align__(16) __bf16 lA[128 * 64];
  __shared__ __align__(16) __bf16 lB[128 * 64];
  const int tid = threadIdx.x;
  const int lane = tid & 63;
  const int wave = tid >> 6;
  const int wr = wave >> 1, wc = wave & 1;
  const int m0 = blockIdx.y * 128, n0 = blockIdx.x * 128;
  const int srow = tid >> 3, kc = tid & 7;  // staging: 8 threads/row, 16B chunks
  const int r16 = lane & 15, g = lane >> 4;
  f32x4 acc[4][4] = {};
  for (int k0 = 0; k0 < K; k0 += 64) {
    u32x4 ra[4], rb[4];
    #pragma unroll
    for (int p = 0; p < 4; ++p) {
      const int row = p * 32 + srow;
      ra[p] = *(const u32x4*)&A[(size_t)(m0 + row) * K + k0 + kc * 8];
      rb[p] = *(const u32x4*)&Bt[(size_t)(n0 + row) * K + k0 + kc * 8];
    }
    __syncthreads();  // prior iter's ds_reads done before overwrite
    #pragma unroll
    for (int p = 0; p < 4; ++p) {
      const int row = p * 32 + srow;
      const int sw = kc ^ (row & 7);  // bank-conflict swizzle (G4)
      *(u32x4*)&lA[row * 64 + sw * 8] = ra[p];
      *(u32x4*)&lB[row * 64 + sw * 8] = rb[p];
    }
    __syncthreads();
    #pragma unroll
    for (int ks = 0; ks < 64; ks += 32) {
      bf16x8 af[4], bfr[4];
      const int kch = (ks >> 3) + g;
      #pragma unroll
      for (int mi = 0; mi < 4; ++mi) {
        const int row = wr * 64 + mi * 16 + r16;
        af[mi] = *(const bf16x8*)&lA[row * 64 + (kch ^ (row & 7)) * 8];
      }
      #pragma unroll
      for (int ni = 0; ni < 4; ++ni) {
        const int row = wc * 64 + ni * 16 + r16;
        bfr[ni] = *(const bf16x8*)&lB[row * 64 + (kch ^ (row & 7)) * 8];
      }
      #pragma unroll
      for (int mi = 0; mi < 4; ++mi)
        #pragma unroll
        for (int ni = 0; ni < 4; ++ni)
          acc[mi][ni] = __builtin_amdgcn_mfma_f32_16x16x32_bf16(af[mi], bfr[ni], acc[mi][ni], 0, 0, 0);
    }
  }
  // epilogue: D layout col=lane&15, row=(lane>>4)*4+j
  #pragma unroll
  for (int mi = 0; mi < 4; ++mi) {
    const int r0 = m0 + wr * 64 + mi * 16 + g * 4;
    #pragma unroll
    for (int ni = 0; ni < 4; ++ni) {
      const int c = n0 + wc * 64 + ni * 16 + r16;
      #pragma unroll
      for (int j = 0; j < 4; ++j)
        C[(size_t)(r0 + j) * N + c] = acc[mi][ni][j];
    }
  }
}

// ---- RoPE on q,k (from fp32 qkv) -> Q[b][h][t][d], K[b][kvh][t][d] bf16 ----
__global__ __launch_bounds__(256) void rope_qk_kernel(const float* __restrict__ qkv,
                                                      const float* __restrict__ cosT,
                                                      const float* __restrict__ sinT,
                                                      __bf16* __restrict__ Q,
                                                      __bf16* __restrict__ Kb) {
  const int idx = blockIdx.x * 256 + threadIdx.x;  // M_*(NH+NKV)*32 total
  const int i = idx & 31;
  const int rest = idx >> 5;
  const int head = rest % (NH_ + NKV_);
  const int row = rest / (NH_ + NKV_);
  const int b = row >> 11, t = row & 2047;
  const float c = cosT[t * 32 + i], s = sinT[t * 32 + i];
  if (head < NH_) {
    const float* p = &qkv[(size_t)row * NQKV_ + head * HD_ + 2 * i];
    const float o1 = p[0] * c - p[1] * s;
    const float o2 = p[0] * s + p[1] * c;
    __bf16* q = &Q[(((size_t)b * NH_ + head) * T_ + t) * HD_ + 2 * i];
    q[0] = (__bf16)o1; q[1] = (__bf16)o2;
  } else {
    const int kh = head - NH_;
    const float* p = &qkv[(size_t)row * NQKV_ + NH_ * HD_ + kh * HD_ + 2 * i];
    const float o1 = p[0] * c - p[1] * s;
    const float o2 = p[0] * s + p[1] * c;
    __bf16* k = &Kb[(((size_t)b * NKV_ + kh) * T_ + t) * HD_ + 2 * i];
    k[0] = (__bf16)o1; k[1] = (__bf16)o2;
  }
}

// ---- V transpose: qkv v-part -> Vt[b][kvh][d][t] bf16 (LDS tiled) ----
__global__ __launch_bounds__(256) void v_transpose_kernel(const float* __restrict__ qkv,
                                                          __bf16* __restrict__ Vt) {
  __shared__ __bf16 tile[64][72];  // [d][t_local], padded
  const int blk = blockIdx.x;      // B*NKV*(T/64)
  const int t0 = (blk & 31) * 64;
  const int kvh = (blk >> 5) & 3;
  const int b = blk >> 7;
  const int tid = threadIdx.x;
  const int tr = tid >> 4, c4 = (tid & 15) << 2;
  #pragma unroll
  for (int p = 0; p < 4; ++p) {
    const int t = t0 + p * 16 + tr;
    const float4 v = *(const float4*)&qkv[(size_t)(b * T_ + t) * NQKV_ + (NH_ + NKV_) * HD_ + kvh * HD_ + c4];
    tile[c4 + 0][p * 16 + tr] = (__bf16)v.x;
    tile[c4 + 1][p * 16 + tr] = (__bf16)v.y;
    tile[c4 + 2][p * 16 + tr] = (__bf16)v.z;
    tile[c4 + 3][p * 16 + tr] = (__bf16)v.w;
  }
  __syncthreads();
  #pragma unroll
  for (int p = 0; p < 4; ++p) {
    const int d = p * 16 + tr;
    bf16x4 o;
    o.x = tile[d][c4 + 0]; o.y = tile[d][c4 + 1];
    o.z = tile[d][c4 + 2]; o.w = tile[d][c4 + 3];
    *(bf16x4*)&Vt[(((size_t)b * NKV_ + kvh) * HD_ + d) * T_ + t0 + c4] = o;
  }
}

// ---- flash attention: 4 waves/block, QBLK=128 (32 q-rows/wave), KVBLK=64 ----
// K and V^T staged in XOR-swizzled LDS shared by all 4 waves; per-wave P bounce
// through swizzled LDS (same-wave DS ops are in-order; no barrier needed).
__global__ __launch_bounds__(256) void attn_kernel(const __bf16* __restrict__ Q,
                                                   const __bf16* __restrict__ Kb,
                                                   const __bf16* __restrict__ Vt,
                                                   __bf16* __restrict__ Y) {
  __shared__ __align__(16) __bf16 lK[64 * 64];       // [kv][d], swizzled
  __shared__ __align__(16) __bf16 lV[64 * 64];       // [d][kv], swizzled
  __shared__ __align__(16) __bf16 pP[4][32 * 64];    // per-wave [q][kv], swizzled
  const int tid = threadIdx.x;
  const int lane = tid & 63, wave = tid >> 6;
  const int r16 = lane & 15, g = lane >> 4;
  const int bq = blockIdx.x;
  const int bh = blockIdx.y;
  const int b = bh >> 4, h = bh & 15;
  const int kvh = h >> 2;  // GQA rep = 4
  const __bf16* Qp = Q + ((size_t)b * NH_ + h) * T_ * HD_;
  const __bf16* Kp = Kb + ((size_t)b * NKV_ + kvh) * T_ * HD_;
  const __bf16* Vp = Vt + ((size_t)b * NKV_ + kvh) * HD_ * T_;
  const int qw = bq * 128 + wave * 32;  // this wave's first q-row
  const int srow = tid >> 3, kc = tid & 7;  // staging: 8x16B chunks per 128B row

  // Q fragments (A-layout), pre-scaled by 1/8 (exact in bf16)
  bf16x8 qf[2][2];
  #pragma unroll
  for (int mi = 0; mi < 2; ++mi)
    #pragma unroll
    for (int c = 0; c < 2; ++c) {
      const bf16x8 t0 = *(const bf16x8*)&Qp[(size_t)(qw + mi * 16 + r16) * HD_ + (c * 4 + g) * 8];
      #pragma unroll
      for (int j = 0; j < 8; ++j) qf[mi][c][j] = (__bf16)((float)t0[j] * 0.125f);
    }

  f32x4 o[2][4] = {};
  float m[2][4], l[2][4];
  #pragma unroll
  for (int mi = 0; mi < 2; ++mi)
    #pragma unroll
    for (int j = 0; j < 4; ++j) { m[mi][j] = -__builtin_inff(); l[mi][j] = 0.0f; }

  const int ntiles = 2 * bq + 2;
  for (int tile = 0; tile < ntiles; ++tile) {
    const int kv0 = tile << 6;
    __syncthreads();  // prior iteration's LDS reads complete before overwrite
    #pragma unroll
    for (int p = 0; p < 2; ++p) {
      const int row = p * 32 + srow;
      const u32x4 kval = *(const u32x4*)&Kp[(size_t)(kv0 + row) * HD_ + kc * 8];
      const u32x4 vval = *(const u32x4*)&Vp[(size_t)row * T_ + kv0 + kc * 8];
      const int sw = (kc ^ (row & 7)) * 8;
      *(u32x4*)&lK[row * 64 + sw] = kval;
      *(u32x4*)&lV[row * 64 + sw] = vval;
    }
    __syncthreads();
    if (kv0 > qw + 31) continue;  // wave-uniform skip; barrier counts stay matched

    // ---- QK^T: S[q][kv], 16 MFMAs ----
    f32x4 s[2][4] = {};
    #pragma unroll
    for (int c = 0; c < 2; ++c) {
      bf16x8 kf[4];
      #pragma unroll
      for (int ni = 0; ni < 4; ++ni) {
        const int row = ni * 16 + r16;
        kf[ni] = *(const bf16x8*)&lK[row * 64 + (((c * 4 + g)) ^ (row & 7)) * 8];
      }
      #pragma unroll
      for (int mi = 0; mi < 2; ++mi)
        #pragma unroll
        for (int ni = 0; ni < 4; ++ni)
          s[mi][ni] = __builtin_amdgcn_mfma_f32_16x16x32_bf16(qf[mi][c], kf[ni], s[mi][ni], 0, 0, 0);
    }

    // ---- causal mask (diagonal-region tiles only) ----
    if (kv0 + 63 > qw) {
      #pragma unroll
      for (int mi = 0; mi < 2; ++mi)
        #pragma unroll
        for (int ni = 0; ni < 4; ++ni)
          #pragma unroll
          for (int j = 0; j < 4; ++j)
            if (kv0 + ni * 16 + r16 > qw + mi * 16 + g * 4 + j) s[mi][ni][j] = -__builtin_inff();
    }

    // ---- online softmax (4 rows in parallel per j-step) + P write ----
    #pragma unroll
    for (int mi = 0; mi < 2; ++mi)
      #pragma unroll
      for (int j = 0; j < 4; ++j) {
        float pm = fmaxf(fmaxf(s[mi][0][j], s[mi][1][j]), fmaxf(s[mi][2][j], s[mi][3][j]));
        #pragma unroll
        for (int off = 8; off; off >>= 1) pm = fmaxf(pm, __shfl_xor(pm, off, 16));
        const float nm = fmaxf(m[mi][j], pm);
        const float sc = __expf(m[mi][j] - nm);
        m[mi][j] = nm;
        float p_[4], rs = 0.0f;
        #pragma unroll
        for (int ni = 0; ni < 4; ++ni) { p_[ni] = __expf(s[mi][ni][j] - nm); rs += p_[ni]; }
        #pragma unroll
        for (int off = 8; off; off >>= 1) rs += __shfl_xor(rs, off, 16);
        l[mi][j] = l[mi][j] * sc + rs;
        #pragma unroll
        for (int nf = 0; nf < 4; ++nf) o[mi][nf][j] *= sc;
        const int rp = mi * 16 + g * 4 + j;
        const int swbase = rp * 64 + (rp & 7) * 8;  // XOR applied to chunk index
        #pragma unroll
        for (int ni = 0; ni < 4; ++ni) {
          const int col = ni * 16 + r16;
          pP[wave][rp * 64 + (((col >> 3) ^ (rp & 7)) * 8) + (col & 7)] = (__bf16)p_[ni];
        }
        (void)swbase;
      }
    asm volatile("s_waitcnt lgkmcnt(0)" ::: "memory");
    __builtin_amdgcn_sched_barrier(0);

    // ---- PV: O += P * V^T, 16 MFMAs ----
    #pragma unroll
    for (int c = 0; c < 2; ++c) {
      bf16x8 pf[2];
      #pragma unroll
      for (int mi = 0; mi < 2; ++mi) {
        const int row = mi * 16 + r16;
        pf[mi] = *(const bf16x8*)&pP[wave][row * 64 + (((c * 4 + g)) ^ (row & 7)) * 8];
      }
      #pragma unroll
      for (int nf = 0; nf < 4; ++nf) {
        const int row = nf * 16 + r16;
        const bf16x8 vf = *(const bf16x8*)&lV[row * 64 + (((c * 4 + g)) ^ (row & 7)) * 8];
        #pragma unroll
        for (int mi = 0; mi < 2; ++mi)
          o[mi][nf] = __builtin_amdgcn_mfma_f32_16x16x32_bf16(pf[mi], vf, o[mi][nf], 0, 0, 0);
      }
    }
  }

  // ---- epilogue -> Y[b][t][h][d] bf16 ----
  #pragma unroll
  for (int mi = 0; mi < 2; ++mi)
    #pragma unroll
    for (int j = 0; j < 4; ++j) {
      const float inv = 1.0f / l[mi][j];
      const int t = qw + mi * 16 + g * 4 + j;
      #pragma unroll
      for (int nf = 0; nf < 4; ++nf) {
        const int d = nf * 16 + r16;
        Y[(((size_t)b * T_ + t) * NH_ + h) * HD_ + d] = (__bf16)(o[mi][nf][j] * inv);
      }
    }
}

extern "C" void kernel_launch(void* const* d_in, const int* in_sizes, int n_in,
                              void* d_out, int out_size, void* d_ws, size_t ws_size,
                              hipStream_t stream) {
  const float* x = (const float*)d_in[0];
  const float* Wqkv = (const float*)d_in[1];
  const float* Wproj = (const float*)d_in[2];
  float* out = (float*)d_out;

  char* ws = (char*)d_ws;
  size_t off = 0;
  auto alloc = [&](size_t bytes) {
    char* p = ws + off;
    off += (bytes + 255) & ~(size_t)255;
    return p;
  };
  __bf16* xb     = (__bf16*)alloc((size_t)M_ * C_ * 2);          // 8 MB
  __bf16* wqkvT  = (__bf16*)alloc((size_t)NQKV_ * C_ * 2);       // 3 MB
  __bf16* wprojT = (__bf16*)alloc((size_t)C_ * C_ * 2);          // 2 MB
  float*  cosT   = (float*)alloc((size_t)T_ * 32 * 4);
  float*  sinT   = (float*)alloc((size_t)T_ * 32 * 4);
  float*  qkv    = (float*)alloc((size_t)M_ * NQKV_ * 4);        // 25 MB
  __bf16* Qb     = (__bf16*)alloc((size_t)B_ * NH_ * T_ * HD_ * 2);
  __bf16* Kb     = (__bf16*)alloc((size_t)B_ * NKV_ * T_ * HD_ * 2);
  __bf16* Vt     = (__bf16*)alloc((size_t)B_ * NKV_ * T_ * HD_ * 2);
  __bf16* Yb     = (__bf16*)alloc((size_t)M_ * C_ * 2);          // 8 MB

  hipLaunchKernelGGL(cast_x_kernel, dim3(M_ * C_ / 4 / 256), dim3(256), 0, stream, x, xb);
  hipLaunchKernelGGL(transpose_cast_kernel, dim3(NQKV_ / 64, C_ / 64), dim3(256), 0, stream,
                     Wqkv, wqkvT, C_, NQKV_);
  hipLaunchKernelGGL(transpose_cast_kernel, dim3(C_ / 64, C_ / 64), dim3(256), 0, stream,
                     Wproj, wprojT, C_, C_);
  hipLaunchKernelGGL(rope_table_kernel, dim3(T_ * 32 / 256), dim3(256), 0, stream, cosT, sinT);
  hipLaunchKernelGGL(gemm_tn_kernel, dim3(NQKV_ / 128, M_ / 128), dim3(256), 0, stream,
                     xb, wqkvT, qkv, NQKV_, C_);
  hipLaunchKernelGGL(rope_qk_kernel, dim3(M_ * (NH_ + NKV_) * 32 / 256), dim3(256), 0, stream,
                     qkv, cosT, sinT, Qb, Kb);
  hipLaunchKernelGGL(v_transpose_kernel, dim3(B_ * NKV_ * (T_ / 64)), dim3(256), 0, stream,
                     qkv, Vt);
  hipLaunchKernelGGL(attn_kernel, dim3(T_ / 128, B_ * NH_), dim3(256), 0, stream, Qb, Kb, Vt, Yb);
  hipLaunchKernelGGL(gemm_tn_kernel, dim3(C_ / 128, M_ / 128), dim3(256), 0, stream,
                     Yb, wprojT, out, C_, C_);
}